// Round 7
// baseline (77.160 us; speedup 1.0000x reference)
//
#include <hip/hip_runtime.h>

// WaveNet single-output inference on MI355X — sparse-tree fused version, v2.
// Only skip_sum[:, :, 8190] matters. Dependency set per layer is an arithmetic
// progression with stride = dilation/2; h_12 never needed.
// Kernel A: in_conv + layers 0-5 per block via exact-fit halo pyramid
//           (96->95->47->23->11->5->2) producing 2 compact h6 outputs.
// Kernel B: layers 6-11 + skip + f1/f2 head, one block per batch, all in LDS.
// v2 change (perf): weight fragments were gathered per-wave per-layer straight
// from global (16B/lane at 128B stride = ~8x sector waste, 480 KB/block) —
// now wn_prep writes weights in XOR-swizzled fragment layout and each layer
// stages 20 KB into LDS with coalesced loads; fragments come from ds_read_b128.

typedef __attribute__((ext_vector_type(8))) short short8;
typedef __attribute__((ext_vector_type(4))) float f32x4;

#define TLAST  8190
#define BATCH  32

__device__ inline ushort bf16hi(float x) {
    union { float f; unsigned u; } v; v.f = x;
    const unsigned u = v.u;
    return (ushort)((u + 0x7fffu + ((u >> 16) & 1u)) >> 16);
}
__device__ inline float bf16f(ushort h) {
    union { unsigned u; float f; } v; v.u = ((unsigned)h) << 16;
    return v.f;
}
__device__ inline int imin(int a, int b) { return a < b ? a : b; }

// ---------------------------------------------------------------- weight prep
// Writes hi/lo bf16 split weights in XOR-swizzled fragment layout:
//   dil: element (n, k) at n*64 + ((k>>3)^(n&7))*8 + (k&7), k = ic + 32*tap
//   res: element (n, k) at n*32 + ((k>>3)^(n&3))*8 + (k&7)
__global__ __launch_bounds__(256) void wn_prep(
    const float* __restrict__ dil_w, const float* __restrict__ res_w,
    ushort* __restrict__ wdh, ushort* __restrict__ wdl,
    ushort* __restrict__ wrh, ushort* __restrict__ wrl)
{
    const int idx = blockIdx.x * 256 + threadIdx.x;
    if (idx < 12 * 4096) {
        const int l = idx >> 12, rem = idx & 4095, n = rem >> 6, k = rem & 63;
        const int tap = k >> 5, ic = k & 31;
        const float v = dil_w[((size_t)l * 64 + n) * 64 + 2 * ic + tap];
        const ushort h = bf16hi(v);
        const int dst = l * 4096 + n * 64 + (((k >> 3) ^ (n & 7)) * 8) + (k & 7);
        wdh[dst] = h;
        wdl[dst] = bf16hi(v - bf16f(h));
    } else if (idx < 12 * 4096 + 12 * 1024) {
        const int j = idx - 12 * 4096;
        const int l = j >> 10, rem = j & 1023, n = rem >> 5, k = rem & 31;
        const float v = res_w[j];
        const ushort h = bf16hi(v);
        const int dst = l * 1024 + n * 32 + (((k >> 3) ^ (n & 3)) * 8) + (k & 7);
        wrh[dst] = h;
        wrl[dst] = bf16hi(v - bf16f(h));
    }
}

// ---------------------------------------------------------------- phase A
// One block = one (chunk, batch): produces h6 at t = t6a, t6a+32.
// Dense window H0: t in [t6a-31, t6a+64] (96 rows). Exact-fit pyramid.
__global__ __launch_bounds__(256) void wn_fuseA(
    const float* __restrict__ x, const float* __restrict__ in_w,
    const float* __restrict__ in_b,
    const ushort* __restrict__ wdh, const ushort* __restrict__ wdl,
    const ushort* __restrict__ wrh, const ushort* __restrict__ wrl,
    const float* __restrict__ dil_b, const float* __restrict__ res_b,
    ushort* __restrict__ c6h, ushort* __restrict__ c6l,
    float* __restrict__ gTL)
{
    __shared__ __align__(16) ushort HAh[96 * 40], HAl[96 * 40];
    __shared__ __align__(16) ushort HBh[96 * 40], HBl[96 * 40];
    __shared__ __align__(16) ushort sGh[4][16 * 40], sGl[4][16 * 40];
    // weight stage pool; xs overlays it (xs dead before first weight stage)
    __shared__ __align__(16) char wpool[20480];
    ushort* sWdh = (ushort*)wpool;              // 8192 B
    ushort* sWdl = (ushort*)(wpool + 8192);     // 8192 B
    ushort* sWrh = (ushort*)(wpool + 16384);    // 2048 B
    ushort* sWrl = (ushort*)(wpool + 18432);    // 2048 B
    float*  xs   = (float*)wpool;               // 7680 B (in_conv only)

    const int tid  = threadIdx.x;
    const int cc   = blockIdx.x, b = blockIdx.y;
    const int lane = tid & 63, w = tid >> 6;
    const int nl   = lane & 15, o = lane >> 4;
    const int t6a  = 6174 + cc * 64;
    const int a0   = t6a - 31;            // global t of H0 row 0

    // ---- stage x (96 pos x 16 ch, fp32)
    for (int i = tid; i < 384; i += 256) {
        const int p = i >> 2, c4 = (i & 3) * 4;
        const int t = a0 + p;
        float4 v = make_float4(0.f, 0.f, 0.f, 0.f);
        if (t <= 8191) v = *(const float4*)&x[((size_t)b * 8192 + t) * 16 + c4];
        *(float4*)&xs[p * 20 + c4] = v;
    }
    __syncthreads();

    // ---- in_conv -> HA (bf16 hi/lo)
    {
        const int c = tid & 31, pg = tid >> 5;
        float wr[16];
        #pragma unroll
        for (int f = 0; f < 16; ++f) wr[f] = in_w[c * 16 + f];
        const float bias = in_b[c];
        #pragma unroll
        for (int q = 0; q < 12; ++q) {
            const int p = pg + 8 * q;     // 0..95
            float acc = bias;
            #pragma unroll
            for (int f4 = 0; f4 < 4; ++f4) {
                const float4 xv = *(const float4*)&xs[p * 20 + f4 * 4];
                acc += wr[f4*4+0]*xv.x + wr[f4*4+1]*xv.y
                     + wr[f4*4+2]*xv.z + wr[f4*4+3]*xv.w;
            }
            const ushort hh = bf16hi(acc);
            HAh[p * 40 + c] = hh;
            HAl[p * 40 + c] = bf16hi(acc - bf16f(hh));
        }
    }
    __syncthreads();   // xs reads done; wpool may be reused for weights

    for (int l = 0; l < 6; ++l) {
        const ushort* Hih = (l & 1) ? HBh : HAh;
        const ushort* Hil = (l & 1) ? HBl : HAl;
        ushort* Hoh = (l & 1) ? HAh : HBh;
        ushort* Hol = (l & 1) ? HAl : HBl;
        const int nIn  = (l == 0) ? 96 : (192 >> l) - 1;
        const int nOut = (192 >> (l + 1)) - 1;            // 95,47,23,11,5,2
        const int nT   = (nOut + 15) >> 4;
        const int sO   = 1 << l;
        const int aO   = a0 + sO - 1;
        const int bOff = (l == 0) ? 1 : (sO >> 1);
        const int rmx  = (l == 0) ? 8191 : TLAST;

        // ---- stage this layer's weights into LDS (coalesced, pre-swizzled)
        {
            const short8* gdh = (const short8*)(wdh + (size_t)l * 4096);
            const short8* gdl = (const short8*)(wdl + (size_t)l * 4096);
            for (int i = tid; i < 512; i += 256) {
                ((short8*)sWdh)[i] = gdh[i];
                ((short8*)sWdl)[i] = gdl[i];
            }
            if (tid < 128) {
                ((short8*)sWrh)[tid] = ((const short8*)(wrh + (size_t)l * 1024))[tid];
                ((short8*)sWrl)[tid] = ((const short8*)(wrl + (size_t)l * 1024))[tid];
            }
        }
        __syncthreads();

        // ---- weight fragments from LDS (XOR-swizzled ds_read_b128)
        short8 Bh[4][2], Bl[4][2], Rh[2], Rl[2];
        #pragma unroll
        for (int nt = 0; nt < 4; ++nt)
            #pragma unroll
            for (int kt = 0; kt < 2; ++kt) {
                const int n = nl + 16 * nt;
                const int u = (kt * 4 + o) ^ (n & 7);
                Bh[nt][kt] = *(const short8*)&sWdh[n * 64 + u * 8];
                Bl[nt][kt] = *(const short8*)&sWdl[n * 64 + u * 8];
            }
        #pragma unroll
        for (int nt = 0; nt < 2; ++nt) {
            const int n = nl + 16 * nt;
            const int u = o ^ (n & 3);
            Rh[nt] = *(const short8*)&sWrh[n * 32 + u * 8];
            Rl[nt] = *(const short8*)&sWrl[n * 32 + u * 8];
        }
        float dbg[2], dbf[2], rbv[2];
        #pragma unroll
        for (int nt = 0; nt < 2; ++nt) {
            dbg[nt] = dil_b[l * 64 + nl + 16 * nt];
            dbf[nt] = dil_b[l * 64 + nl + 16 * nt + 32];
            rbv[nt] = res_b[l * 32 + nl + 16 * nt];
        }

        for (int tt = w; tt < nT; tt += 4) {
            // ---- A fragments from LDS (compact taps)
            const int joF = tt * 16 + nl;
            const int j0 = imin((l == 0) ? joF : 2 * joF, nIn - 1);
            const int j1 = imin((l == 0) ? joF + 1 : 2 * joF + 2, nIn - 1);
            const bool zB = (aO + joF * sO + bOff) > rmx;
            const short8 z8 = {0,0,0,0,0,0,0,0};
            short8 Ah[2], Al[2];
            Ah[0] = *(const short8*)&Hih[j0 * 40 + o * 8];
            Al[0] = *(const short8*)&Hil[j0 * 40 + o * 8];
            Ah[1] = zB ? z8 : *(const short8*)&Hih[j1 * 40 + o * 8];
            Al[1] = zB ? z8 : *(const short8*)&Hil[j1 * 40 + o * 8];

            // ---- gate/filt GEMM (bf16-split, 24 MFMAs)
            f32x4 acc[4] = {{0,0,0,0},{0,0,0,0},{0,0,0,0},{0,0,0,0}};
            #pragma unroll
            for (int kt = 0; kt < 2; ++kt)
                #pragma unroll
                for (int nt = 0; nt < 4; ++nt) {
                    acc[nt] = __builtin_amdgcn_mfma_f32_16x16x32_bf16(Ah[kt], Bh[nt][kt], acc[nt], 0, 0, 0);
                    acc[nt] = __builtin_amdgcn_mfma_f32_16x16x32_bf16(Ah[kt], Bl[nt][kt], acc[nt], 0, 0, 0);
                    acc[nt] = __builtin_amdgcn_mfma_f32_16x16x32_bf16(Al[kt], Bh[nt][kt], acc[nt], 0, 0, 0);
                }

            // ---- activation + per-wave G transpose + gTL capture
            #pragma unroll
            for (int nt = 0; nt < 2; ++nt)
                #pragma unroll
                for (int r = 0; r < 4; ++r) {
                    const float gate = acc[nt][r]     + dbg[nt];
                    const float filt = acc[nt + 2][r] + dbf[nt];
                    const float sg = 1.f / (1.f + __expf(-gate));
                    const float th = 2.f / (1.f + __expf(-2.f * filt)) - 1.f;
                    const float g  = th * sg;
                    const int ml = 4 * o + r;
                    const int n  = nl + 16 * nt;
                    const ushort gh = bf16hi(g);
                    sGh[w][ml * 40 + n] = gh;
                    sGl[w][ml * 40 + n] = bf16hi(g - bf16f(gh));
                    const int joG = tt * 16 + ml;
                    if (joG < nOut && (aO + joG * sO) == TLAST)
                        gTL[((size_t)l * BATCH + b) * 32 + n] = g;
                }

            // ---- res GEMM (6 MFMAs, same-wave LDS, no barrier)
            const short8 Gh8 = *(const short8*)&sGh[w][nl * 40 + o * 8];
            const short8 Gl8 = *(const short8*)&sGl[w][nl * 40 + o * 8];
            f32x4 accR[2] = {{0,0,0,0},{0,0,0,0}};
            #pragma unroll
            for (int nt = 0; nt < 2; ++nt) {
                accR[nt] = __builtin_amdgcn_mfma_f32_16x16x32_bf16(Gh8, Rh[nt], accR[nt], 0, 0, 0);
                accR[nt] = __builtin_amdgcn_mfma_f32_16x16x32_bf16(Gh8, Rl[nt], accR[nt], 0, 0, 0);
                accR[nt] = __builtin_amdgcn_mfma_f32_16x16x32_bf16(Gl8, Rh[nt], accR[nt], 0, 0, 0);
            }

            // ---- epilogue: + bias + residual (compact idx 2j+1), store
            #pragma unroll
            for (int nt = 0; nt < 2; ++nt)
                #pragma unroll
                for (int r = 0; r < 4; ++r) {
                    const int ml  = 4 * o + r;
                    const int joE = tt * 16 + ml;
                    const int jres = imin((l == 0) ? joE + 1 : 2 * joE + 1, nIn - 1);
                    const int n = nl + 16 * nt;
                    const float resv = bf16f(Hih[jres * 40 + n]) + bf16f(Hil[jres * 40 + n]);
                    const float hv = accR[nt][r] + rbv[nt] + resv;
                    const ushort hh = bf16hi(hv);
                    const ushort hl = bf16hi(hv - bf16f(hh));
                    Hoh[joE * 40 + n] = hh;
                    Hol[joE * 40 + n] = hl;
                    if (l == 5 && joE < 2) {
                        const size_t go = ((size_t)b * 64 + cc * 2 + joE) * 32 + n;
                        c6h[go] = hh;
                        c6l[go] = hl;
                    }
                }
        }
        __syncthreads();
    }
}

// ---------------------------------------------------------------- phase B
// One block per batch: layers 6-11 (compact, in LDS) + skip sum + f1/f2 head.
__global__ __launch_bounds__(256) void wn_fuseB(
    const ushort* __restrict__ c6h, const ushort* __restrict__ c6l,
    const ushort* __restrict__ wdh, const ushort* __restrict__ wdl,
    const ushort* __restrict__ wrh, const ushort* __restrict__ wrl,
    const float* __restrict__ dil_b, const float* __restrict__ res_b,
    const float* __restrict__ gTL,
    const float* __restrict__ sw, const float* __restrict__ sb,
    const float* __restrict__ f1w, const float* __restrict__ f1b,
    const float* __restrict__ f2w, const float* __restrict__ f2b,
    float* __restrict__ out)
{
    __shared__ __align__(16) ushort HAh[64 * 40], HAl[64 * 40];
    __shared__ __align__(16) ushort HBh[64 * 40], HBl[64 * 40];
    __shared__ __align__(16) ushort sGh[4][16 * 40], sGl[4][16 * 40];
    __shared__ __align__(16) ushort sWdh[4096], sWdl[4096];
    __shared__ __align__(16) ushort sWrh[1024], sWrl[1024];
    __shared__ float gcap[6][33];
    __shared__ float ss[32], z1[32];

    const int tid  = threadIdx.x, b = blockIdx.x;
    const int lane = tid & 63, w = tid >> 6;
    const int nl   = lane & 15, o = lane >> 4;

    // stage c6 (4 short8 chunks per 32-channel row)
    for (int i = tid; i < 256; i += 256) {
        const int row = i >> 2, c8 = (i & 3) * 8;
        *(short8*)&HAh[row * 40 + c8] = *(const short8*)&c6h[((size_t)b * 64 + row) * 32 + c8];
        *(short8*)&HAl[row * 40 + c8] = *(const short8*)&c6l[((size_t)b * 64 + row) * 32 + c8];
    }
    __syncthreads();

    for (int ll = 0; ll < 6; ++ll) {
        const int l = ll + 6;
        const ushort* Hih = (ll & 1) ? HBh : HAh;
        const ushort* Hil = (ll & 1) ? HBl : HAl;
        ushort* Hoh = (ll & 1) ? HAh : HBh;
        ushort* Hol = (ll & 1) ? HAl : HBl;
        const int nIn  = 64 >> ll;
        const int nOut = 32 >> ll;
        const int nT   = (nOut + 15) >> 4;
        const int sO   = 64 << ll;
        const int aO   = 6142 + sO;
        const int bOff = sO >> 1;

        // ---- stage weights into LDS (coalesced, pre-swizzled)
        {
            const short8* gdh = (const short8*)(wdh + (size_t)l * 4096);
            const short8* gdl = (const short8*)(wdl + (size_t)l * 4096);
            for (int i = tid; i < 512; i += 256) {
                ((short8*)sWdh)[i] = gdh[i];
                ((short8*)sWdl)[i] = gdl[i];
            }
            if (tid < 128) {
                ((short8*)sWrh)[tid] = ((const short8*)(wrh + (size_t)l * 1024))[tid];
                ((short8*)sWrl)[tid] = ((const short8*)(wrl + (size_t)l * 1024))[tid];
            }
        }
        __syncthreads();

        short8 Bh[4][2], Bl[4][2], Rh[2], Rl[2];
        #pragma unroll
        for (int nt = 0; nt < 4; ++nt)
            #pragma unroll
            for (int kt = 0; kt < 2; ++kt) {
                const int n = nl + 16 * nt;
                const int u = (kt * 4 + o) ^ (n & 7);
                Bh[nt][kt] = *(const short8*)&sWdh[n * 64 + u * 8];
                Bl[nt][kt] = *(const short8*)&sWdl[n * 64 + u * 8];
            }
        #pragma unroll
        for (int nt = 0; nt < 2; ++nt) {
            const int n = nl + 16 * nt;
            const int u = o ^ (n & 3);
            Rh[nt] = *(const short8*)&sWrh[n * 32 + u * 8];
            Rl[nt] = *(const short8*)&sWrl[n * 32 + u * 8];
        }
        float dbg[2], dbf[2], rbv[2];
        #pragma unroll
        for (int nt = 0; nt < 2; ++nt) {
            dbg[nt] = dil_b[l * 64 + nl + 16 * nt];
            dbf[nt] = dil_b[l * 64 + nl + 16 * nt + 32];
            rbv[nt] = res_b[l * 32 + nl + 16 * nt];
        }

        for (int tt = w; tt < nT; tt += 4) {
            const int joF = tt * 16 + nl;
            const int j0 = imin(2 * joF, nIn - 1);
            const int j1 = imin(2 * joF + 2, nIn - 1);
            const bool zB = (aO + joF * sO + bOff) > TLAST;
            const short8 z8 = {0,0,0,0,0,0,0,0};
            short8 Ah[2], Al[2];
            Ah[0] = *(const short8*)&Hih[j0 * 40 + o * 8];
            Al[0] = *(const short8*)&Hil[j0 * 40 + o * 8];
            Ah[1] = zB ? z8 : *(const short8*)&Hih[j1 * 40 + o * 8];
            Al[1] = zB ? z8 : *(const short8*)&Hil[j1 * 40 + o * 8];

            f32x4 acc[4] = {{0,0,0,0},{0,0,0,0},{0,0,0,0},{0,0,0,0}};
            #pragma unroll
            for (int kt = 0; kt < 2; ++kt)
                #pragma unroll
                for (int nt = 0; nt < 4; ++nt) {
                    acc[nt] = __builtin_amdgcn_mfma_f32_16x16x32_bf16(Ah[kt], Bh[nt][kt], acc[nt], 0, 0, 0);
                    acc[nt] = __builtin_amdgcn_mfma_f32_16x16x32_bf16(Ah[kt], Bl[nt][kt], acc[nt], 0, 0, 0);
                    acc[nt] = __builtin_amdgcn_mfma_f32_16x16x32_bf16(Al[kt], Bh[nt][kt], acc[nt], 0, 0, 0);
                }

            #pragma unroll
            for (int nt = 0; nt < 2; ++nt)
                #pragma unroll
                for (int r = 0; r < 4; ++r) {
                    const float gate = acc[nt][r]     + dbg[nt];
                    const float filt = acc[nt + 2][r] + dbf[nt];
                    const float sg = 1.f / (1.f + __expf(-gate));
                    const float th = 2.f / (1.f + __expf(-2.f * filt)) - 1.f;
                    const float g  = th * sg;
                    const int ml = 4 * o + r;
                    const int n  = nl + 16 * nt;
                    const ushort gh = bf16hi(g);
                    sGh[w][ml * 40 + n] = gh;
                    sGl[w][ml * 40 + n] = bf16hi(g - bf16f(gh));
                    const int joG = tt * 16 + ml;
                    if (joG < nOut && (aO + joG * sO) == TLAST)
                        gcap[ll][n] = g;
                }

            if (ll < 5) {
                const short8 Gh8 = *(const short8*)&sGh[w][nl * 40 + o * 8];
                const short8 Gl8 = *(const short8*)&sGl[w][nl * 40 + o * 8];
                f32x4 accR[2] = {{0,0,0,0},{0,0,0,0}};
                #pragma unroll
                for (int nt = 0; nt < 2; ++nt) {
                    accR[nt] = __builtin_amdgcn_mfma_f32_16x16x32_bf16(Gh8, Rh[nt], accR[nt], 0, 0, 0);
                    accR[nt] = __builtin_amdgcn_mfma_f32_16x16x32_bf16(Gh8, Rl[nt], accR[nt], 0, 0, 0);
                    accR[nt] = __builtin_amdgcn_mfma_f32_16x16x32_bf16(Gl8, Rh[nt], accR[nt], 0, 0, 0);
                }
                #pragma unroll
                for (int nt = 0; nt < 2; ++nt)
                    #pragma unroll
                    for (int r = 0; r < 4; ++r) {
                        const int ml  = 4 * o + r;
                        const int joE = tt * 16 + ml;
                        const int jres = imin(2 * joE + 1, nIn - 1);
                        const int n = nl + 16 * nt;
                        const float resv = bf16f(Hih[jres * 40 + n]) + bf16f(Hil[jres * 40 + n]);
                        const float hv = accR[nt][r] + rbv[nt] + resv;
                        const ushort hh = bf16hi(hv);
                        Hoh[joE * 40 + n] = hh;
                        Hol[joE * 40 + n] = bf16hi(hv - bf16f(hh));
                    }
            }
        }
        __syncthreads();
    }

    // ---- skip sum + head (per batch)
    if (tid < 32) {
        const int c = tid;
        float acc = 0.f;
        #pragma unroll
        for (int l2 = 0; l2 < 12; ++l2) {
            float a = sb[l2 * 32 + c];
            #pragma unroll
            for (int ic = 0; ic < 32; ++ic) {
                const float gv = (l2 < 6) ? gTL[((size_t)l2 * BATCH + b) * 32 + ic]
                                          : gcap[l2 - 6][ic];
                a += sw[l2 * 1024 + c * 32 + ic] * gv;
            }
            acc += a;
        }
        ss[c] = fmaxf(acc, 0.f);
    }
    __syncthreads();
    if (tid < 32) {
        float z = f1b[tid];
        #pragma unroll
        for (int ic = 0; ic < 32; ++ic) z += f1w[tid * 32 + ic] * ss[ic];
        z1[tid] = fmaxf(z, 0.f);
    }
    __syncthreads();
    if (tid == 0) {
        float o2 = f2b[0];
        #pragma unroll
        for (int ic = 0; ic < 32; ++ic) o2 += f2w[ic] * z1[ic];
        out[b] = o2;
    }
}

// ---------------------------------------------------------------- launch
extern "C" void kernel_launch(void* const* d_in, const int* in_sizes, int n_in,
                              void* d_out, int out_size, void* d_ws, size_t ws_size,
                              hipStream_t stream)
{
    const float* x      = (const float*)d_in[0];
    const float* in_w   = (const float*)d_in[1];
    const float* in_b   = (const float*)d_in[2];
    const float* dil_w  = (const float*)d_in[3];
    const float* dil_b  = (const float*)d_in[4];
    const float* skip_w = (const float*)d_in[5];
    const float* skip_b = (const float*)d_in[6];
    const float* res_w  = (const float*)d_in[7];
    const float* res_b  = (const float*)d_in[8];
    const float* f1_w   = (const float*)d_in[9];
    const float* f1_b   = (const float*)d_in[10];
    const float* f2_w   = (const float*)d_in[11];
    const float* f2_b   = (const float*)d_in[12];

    char* p = (char*)d_ws;
    ushort* wdh = (ushort*)p; p += 12 * 4096 * 2;
    ushort* wdl = (ushort*)p; p += 12 * 4096 * 2;
    ushort* wrh = (ushort*)p; p += 12 * 1024 * 2;
    ushort* wrl = (ushort*)p; p += 12 * 1024 * 2;
    ushort* c6h = (ushort*)p; p += 32 * 64 * 32 * 2;
    ushort* c6l = (ushort*)p; p += 32 * 64 * 32 * 2;
    float*  gTL = (float*)p;                 // [12][32][32]

    wn_prep<<<dim3((12 * 4096 + 12 * 1024 + 255) / 256), dim3(256), 0, stream>>>(
        dil_w, res_w, wdh, wdl, wrh, wrl);

    wn_fuseA<<<dim3(32, BATCH), dim3(256), 0, stream>>>(
        x, in_w, in_b, wdh, wdl, wrh, wrl, dil_b, res_b, c6h, c6l, gTL);

    wn_fuseB<<<dim3(BATCH), dim3(256), 0, stream>>>(
        c6h, c6l, wdh, wdl, wrh, wrl, dil_b, res_b, gTL,
        skip_w, skip_b, f1_w, f1_b, f2_w, f2_b, (float*)d_out);
}